// Round 4
// baseline (738.698 us; speedup 1.0000x reference)
//
#include <hip/hip_runtime.h>
#include <stdint.h>

typedef __attribute__((ext_vector_type(8))) short bf16x8_t;
typedef __attribute__((ext_vector_type(4))) float f32x4_t;
typedef __attribute__((ext_vector_type(4))) unsigned int u32x4_t;

#define B_ 16
#define C_ 128
#define O_ 256
#define H_ 96
#define W_ 96
#define HO_ 92
#define WO_ 92

// workspace offsets (bytes), total ~79.9 MB (unchanged footprint)
#define XMU_OFF 0UL
#define XSG_OFF 37748736UL
#define WP_OFF  75497472UL
#define W2P_OFF 77135872UL
#define SP_OFF  78774272UL   // unused (softplus folded into k_conv)
#define T_OFF   78775296UL
#define S_OFF   79365120UL   // unused (box-sum folded into k_conv)

__device__ __forceinline__ unsigned short f2bf(float f) {
  unsigned u = __float_as_uint(f);
  u += 0x7fffu + ((u >> 16) & 1u);   // RNE (inputs finite)
  return (unsigned short)(u >> 16);
}

#if defined(__has_builtin)
#if __has_builtin(__builtin_amdgcn_global_load_lds)
#define USE_GLL 1
#endif
#endif
#ifndef USE_GLL
#define USE_GLL 0
#endif

// 16B per lane: LDS dest = wave-uniform base + lane*16 (HW rule); global addr per-lane.
__device__ __forceinline__ void stage16(unsigned short* lds_base, const unsigned short* gp, int lane) {
#if USE_GLL
  __builtin_amdgcn_global_load_lds(
      (const __attribute__((address_space(1))) void*)gp,
      (__attribute__((address_space(3))) void*)lds_base, 16, 0, 0);
#else
  *((u32x4_t*)lds_base + lane) = *(const u32x4_t*)gp;
#endif
}

// ---------------- prep kernels ----------------

// pack W -> [t25][cc4][o][32c] bf16, and W^2 likewise. Coalesced rewrite:
// old version did one stride-100B load per lane (64 scattered lines/wave).
// New: 128 blocks x 2 o-rows; contiguous f32 loads -> LDS (stride-25 reads
// are conflict-free, gcd(25,32)=1) -> 64B-segment writes.
// Also zeros t[147456] (runs before k_cast in-stream, so its atomics are safe).
__global__ void k_packw(const float* __restrict__ W, unsigned short* __restrict__ Wp,
                        unsigned short* __restrict__ W2p, float* __restrict__ t) {
  __shared__ float wl[6400];
  const int tid = threadIdx.x;
  // zero t spread over the 128 blocks (replaces k_zero launch)
  {
    int idx = blockIdx.x * 256 + tid;
#pragma unroll
    for (int k = 0; k < 5; ++k) {
      int j = idx + k * 32768;
      if (j < 147456) t[j] = 0.0f;
    }
  }
  const int o0 = blockIdx.x * 2;
  const float* Wo = W + (size_t)o0 * 3200;
#pragma unroll
  for (int i = 0; i < 25; ++i)
    wl[i * 256 + tid] = Wo[i * 256 + tid];
  __syncthreads();
  const int o1 = tid >> 7;          // 0..1
  const int c  = tid & 127;
  const int cc4 = c >> 5, ci = c & 31;
  const float* src = wl + o1 * 3200 + c * 25;
  const size_t dbase = (size_t)cc4 * 8192 + (size_t)(o0 + o1) * 32 + ci;
#pragma unroll
  for (int t25 = 0; t25 < 25; ++t25) {
    float w = src[t25];
    size_t a = (size_t)t25 * 32768 + dbase;
    Wp[a]  = f2bf(w);
    W2p[a] = f2bf(w * w);
  }
}

// NCHW fp32 -> NHWC bf16 + fused per-row channel sums:
//   mu-block adds sum_c mu^2 to t[b,h,w]; sg-block adds sum_c sg.
// Two atomic contributors per address (a+b == b+a) -> deterministic.
__global__ void k_cast(const float* __restrict__ mu, const float* __restrict__ sg,
                       unsigned short* __restrict__ Xmu, unsigned short* __restrict__ Xsg,
                       float* __restrict__ t) {
  __shared__ float sl[128 * 97];
  __shared__ float part[192];
  int bh = blockIdx.x;
  int b = bh / 96, h = bh - b * 96;
  const int is_mu = (blockIdx.y == 0);
  const float* src = is_mu ? mu : sg;
  unsigned short* dst = is_mu ? Xmu : Xsg;
  int tid = threadIdx.x;
#pragma unroll
  for (int i = 0; i < 12; ++i) {
    int f4 = tid + i * 256;            // 3072 float4 chunks
    int c = f4 / 24, w4 = f4 - c * 24;
    f32x4_t v = *(const f32x4_t*)(src + (((size_t)b * 128 + c) * 96 + h) * 96 + w4 * 4);
    float* s = sl + c * 97 + w4 * 4;
    s[0] = v.x; s[1] = v.y; s[2] = v.z; s[3] = v.w;
  }
  __syncthreads();
  unsigned short* drow = dst + ((size_t)b * 96 + h) * (size_t)(96 * 128);
#pragma unroll
  for (int i = 0; i < 6; ++i) {
    int chunk = tid + i * 256;         // 1536 chunks of 8 bf16
    int w = chunk >> 4;
    int c0 = (chunk & 15) * 8;
    u32x4_t pk;
#pragma unroll
    for (int e = 0; e < 4; ++e) {
      unsigned lo = f2bf(sl[(c0 + 2 * e) * 97 + w]);
      unsigned hi = f2bf(sl[(c0 + 2 * e + 1) * 97 + w]);
      pk[e] = lo | (hi << 16);
    }
    *(u32x4_t*)(drow + (size_t)w * 128 + c0) = pk;
  }
  // fused channel-sum partials
  if (tid < 192) {
    int half = tid / 96, w = tid - half * 96;
    float s = 0.f;
#pragma unroll 4
    for (int c = half * 64; c < half * 64 + 64; ++c) {
      float v = sl[c * 97 + w];
      s += is_mu ? v * v : v;
    }
    part[tid] = s;
  }
  __syncthreads();
  if (tid < 96)
    atomicAdd(&t[((size_t)b * 96 + h) * 96 + tid], part[tid] + part[96 + tid]);
}

// ---------------- main conv (implicit GEMM, bf16 MFMA) ----------------
// block = one output row (b,y): TM=96 (x padded, store x<92), TN=256.
// R0 structure (2 barriers/kh, 20 barrier-free k-steps, epilogue barriers)
// + T1 bijective chunked XCD swizzle (FETCH 233->89MB, MfmaUtil 44->50,
//   confirmed R3) + T5 setprio around MFMA clusters.
// R4: folds softplus (was k_sp) and the 5x5 box-sum of t (was k_S) into
// this kernel -- prologue Srow compute is once per sigma-block, hidden
// before the first barrier; main loop untouched.
__global__ __launch_bounds__(256, 2) void k_conv(
    const unsigned short* __restrict__ Xmu, const unsigned short* __restrict__ Xsg,
    const unsigned short* __restrict__ Wp,  const unsigned short* __restrict__ W2p,
    const float* __restrict__ bias, const float* __restrict__ wsig,
    const float* __restrict__ tb, float* __restrict__ out) {
  __shared__ char smem[25600];                       // A row 24576 B; epi reuses 25600
  __shared__ __align__(16) float SrowL[96];          // 5x5 box-sum of t for this (b,y)
  unsigned short* Alds = (unsigned short*)smem;      // [96 p][16 chunks of 16B], chunk^= (p&15)

  const int mode = blockIdx.y;                       // 0: mu path, 1: sigma path
  const unsigned short* X   = mode ? Xsg : Xmu;
  const unsigned short* Wt0 = mode ? W2p : Wp;

  // T1: chunked XCD swizzle. 1472 = 8 * 184 exactly -> bijective.
  const int bid0 = blockIdx.x;
  const int bid  = (bid0 & 7) * 184 + (bid0 >> 3);
  const int b = bid / HO_;
  const int y = bid - b * HO_;

  const int tid  = threadIdx.x;
  const int wv   = tid >> 6;
  const int lane = tid & 63;
  const int l15  = lane & 15;
  const int g4   = lane >> 4;

  // fold of k_S: sigma blocks compute their row's 5x5 box sums once.
  // 50 L2-hot loads, hidden before the first kh barrier; visible to all
  // threads by the time the (post-many-barriers) epilogue reads it.
  if (mode && tid < WO_) {
    const float* tp = tb + (size_t)b * 9216 + (size_t)y * 96 + tid;
    float s = 0.f;
#pragma unroll
    for (int kh = 0; kh < 5; ++kh) {
      const float* row = tp + kh * 96;
#pragma unroll
      for (int kw = 0; kw < 5; ++kw) s += row[kw];
    }
    SrowL[tid] = s;
  }

  // staging lane decomposition: 1 KB chunk = 4 pixels x 256 B
  const int p_st = lane >> 4;        // pixel within chunk
  const int q_st = lane & 15;        // physical 16B slot within 256B row

  f32x4_t acc[6][4];
#pragma unroll
  for (int im = 0; im < 6; ++im)
#pragma unroll
    for (int in = 0; in < 4; ++in)
      acc[im][in] = (f32x4_t)0.0f;

  const int bo = (wv * 64 + l15) * 32 + g4 * 8;      // B frag base offset (ushorts)

  for (int kh = 0; kh < 5; ++kh) {
    const unsigned short* Xrow = X + ((size_t)(b * H_ + y + kh) * W_) * C_;
    __syncthreads();                                 // prev kh's frag reads done
    // stage 24 chunks of 1 KB round-robin over 4 waves
#pragma unroll
    for (int jj = 0; jj < 6; ++jj) {
      const int j = wv + jj * 4;
      const int p = j * 4 + p_st;
      const int c0 = (q_st ^ (p & 15)) * 8;          // swizzled channel slot
      stage16(Alds + j * 512, Xrow + p * C_ + c0, lane);
    }
    __syncthreads();                                 // staged data visible
#pragma unroll
    for (int kw = 0; kw < 5; ++kw) {
      const unsigned short* Wt = Wt0 + (size_t)(kh * 5 + kw) * 32768;
      int prow[6], pxor[6];
#pragma unroll
      for (int im = 0; im < 6; ++im) {
        int p = im * 16 + l15 + kw;
        p = p < 95 ? p : 95;                         // x>=92 is padding, never stored
        prow[im] = p << 7;                           // row base in ushorts (128/row)
        pxor[im] = p & 15;
      }
#pragma unroll
      for (int cc = 0; cc < 4; ++cc) {
        bf16x8_t bfr[4];
#pragma unroll
        for (int in = 0; in < 4; ++in)
          bfr[in] = *(const bf16x8_t*)(Wt + cc * 8192 + in * 512 + bo);
        bf16x8_t af[6];
        const int cl = cc * 4 + g4;
#pragma unroll
        for (int im = 0; im < 6; ++im)
          af[im] = *(const bf16x8_t*)(Alds + prow[im] + ((cl ^ pxor[im]) << 3));
        __builtin_amdgcn_s_setprio(1);               // T5: favor MFMA cluster
#pragma unroll
        for (int im = 0; im < 6; ++im)
#pragma unroll
          for (int in = 0; in < 4; ++in)
            acc[im][in] = __builtin_amdgcn_mfma_f32_16x16x32_bf16(af[im], bfr[in], acc[im][in], 0, 0, 0);
        __builtin_amdgcn_s_setprio(0);
      }
    }
  }

  // epilogue: transpose through LDS so stores are x-contiguous dwordx4
  float* epi = (float*)smem + wv * 1600;             // [16 o][100 x-padded] per wave
  const size_t outbase = (size_t)mode * ((size_t)B_ * O_ * HO_ * WO_);
  const int orow = lane >> 2, seg = lane & 3;
#pragma unroll
  for (int in = 0; in < 4; ++in) {
    __syncthreads();
#pragma unroll
    for (int im = 0; im < 6; ++im)
#pragma unroll
      for (int r = 0; r < 4; ++r)
        epi[l15 * 100 + im * 16 + g4 * 4 + r] = acc[im][in][r];  // C/D: col=lane&15(=o), row=g4*4+r(=x)
    __syncthreads();
    const int o = wv * 64 + in * 16 + orow;
    // fold of k_sp: softplus computed here (identical formula/order per o
    // across blocks -> deterministic)
    const float scal = mode ? log1pf(expf(fmaxf(wsig[o], -88.0f))) : bias[o];
    const float* erow = epi + orow * 100;
    float* optr = out + outbase + ((size_t)(b * O_ + o) * HO_ + y) * WO_;
#pragma unroll
    for (int jq = 0; jq < 6; ++jq) {
      int q = jq * 4 + seg;
      if (q < 23) {                                  // 92 = 23*4, drop x>=92 padding
        f32x4_t v = *(const f32x4_t*)(erow + q * 4);
        int x = q * 4;
        if (mode) {
          f32x4_t s4 = *(const f32x4_t*)(SrowL + x); // 16B-aligned (x = 4*q)
          v = (scal * s4 + v) * 0.001f;
        } else {
          v = v + scal;
        }
        *(f32x4_t*)(optr + x) = v;
      }
    }
  }
}

extern "C" void kernel_launch(void* const* d_in, const int* in_sizes, int n_in,
                              void* d_out, int out_size, void* d_ws, size_t ws_size,
                              hipStream_t stream) {
  const float* mu   = (const float*)d_in[0];
  const float* sg   = (const float*)d_in[1];
  const float* W    = (const float*)d_in[2];
  const float* bias = (const float*)d_in[3];
  const float* wsig = (const float*)d_in[4];
  float* out = (float*)d_out;
  char* ws = (char*)d_ws;

  unsigned short* Xmu = (unsigned short*)(ws + XMU_OFF);
  unsigned short* Xsg = (unsigned short*)(ws + XSG_OFF);
  unsigned short* Wp  = (unsigned short*)(ws + WP_OFF);
  unsigned short* W2p = (unsigned short*)(ws + W2P_OFF);
  float* tb = (float*)(ws + T_OFF);

  // 3 launches (was 6): packw(+zero t), cast(+channel sums), conv(+softplus,+box-sum)
  k_packw<<<128, 256, 0, stream>>>(W, Wp, W2p, tb);
  k_cast<<<dim3(1536, 2), 256, 0, stream>>>(mu, sg, Xmu, Xsg, tb);
  k_conv<<<dim3(B_ * HO_, 2), 256, 0, stream>>>(Xmu, Xsg, Wp, W2p, bias, wsig, tb, out);
}